// Round 8
// baseline (354.755 us; speedup 1.0000x reference)
//
#include <hip/hip_runtime.h>
#include <cstdint>
#include <cstddef>

#define NF 256   // features
#define NG 512   // hidden (2F)
#define NC 64    // classes
#define NB 8192  // batch
#define NK 16    // active rules
#define BT 64    // fs batch tile
#define NT 4     // tiles per persistent fs block

typedef __attribute__((ext_vector_type(8))) short short8;
typedef __attribute__((ext_vector_type(4))) float floatx4;

__device__ __forceinline__ unsigned short f2bf(float f) {
    union { float f; unsigned int u; } a; a.f = f;
    unsigned int u = a.u;
    u += 0x7fffu + ((u >> 16) & 1u);   // RNE
    return (unsigned short)(u >> 16);
}
__device__ __forceinline__ float elu1(float z) {
    return z > 0.0f ? z : (__expf(z) - 1.0f);
}

// LDS-only barrier: orders ds ops across the workgroup WITHOUT draining vmcnt.
__device__ __forceinline__ void bar_lds() {
    __builtin_amdgcn_sched_barrier(0);
    asm volatile("s_waitcnt lgkmcnt(0)" ::: "memory");
    __builtin_amdgcn_s_barrier();
    __builtin_amdgcn_sched_barrier(0);
}

// ELU + bias + bf16-pack + swizzled LDS store for one mi-row of an acc tile.
__device__ __forceinline__ void elu_write_row(
    unsigned short* dst, const floatx4* acc, float4 b4, int nl, int ln, int sxr)
{
#pragma unroll
    for (int ni = 0; ni < 4; ++ni) {
        union { unsigned short s[4]; uint2 v; } pk;
        pk.s[0] = f2bf(elu1(acc[ni][0] + b4.x));
        pk.s[1] = f2bf(elu1(acc[ni][1] + b4.y));
        pk.s[2] = f2bf(elu1(acc[ni][2] + b4.z));
        pk.s[3] = f2bf(elu1(acc[ni][3] + b4.w));
        *(uint2*)((char*)dst + (ni * 16 + ln) * 512 + ((nl * 2) ^ sxr)) = pk.v;
    }
}

// one membership iteration: 4 features of one batch row -> swizzled LDS
__device__ __forceinline__ void p0_iter(
    unsigned short* dst, const float* xrow, int row, int colb,
    float4 p4, float ix, float iy, float iz, float iw)
{
    const float4 xv = *(const float4*)xrow;
    float dx = xv.x - p4.x, dy = xv.y - p4.y, dz = xv.z - p4.z, dw = xv.w - p4.w;
    union { unsigned short s[4]; uint2 v; } pk;
    pk.s[0] = f2bf(__expf(-dx * dx * ix));
    pk.s[1] = f2bf(__expf(-dy * dy * iy));
    pk.s[2] = f2bf(__expf(-dz * dz * iz));
    pk.s[3] = f2bf(__expf(-dw * dw * iw));
    *(uint2*)((char*)dst + row * 512 + (colb ^ ((row & 7) << 4))) = pk.v;
}

// ---------------- kernel 0: weights fp32 -> bf16 in workspace ----------------
__global__ __launch_bounds__(256) void conv_kernel(
    const float* __restrict__ W1, const float* __restrict__ W2,
    const float* __restrict__ Wc, unsigned short* __restrict__ wb)
{
    int i = blockIdx.x * 256 + threadIdx.x;
    if (i < 131072)       wb[i] = f2bf(W1[i]);
    else if (i < 262144)  wb[i] = f2bf(W2[i - 131072]);
    else if (i < 786432)  wb[i] = f2bf(Wc[i - 262144]);
}

// ---------------- kernel 1: fused membership -> MLP -> fsi (persistent) ------
// grid: 512 blocks = 16 rules x 32 super-tiles; each block processes NT=4
// consecutive 64-row tiles of one rule. Cross-tile pipeline: during tile t's
// P2-chunk1 MFMA steps, tile t+1's membership (P0') is computed into the
// buffer freed after P2-chunk0 -> P0 leaves the serial chain for 3 of 4
// tiles. Rule constants (proto/var/clip) loaded once per block. Buffers
// ping-pong by tile parity; FP math per value identical to round 4/6.
__global__ __launch_bounds__(256, 2) void fs_kernel(
    const float* __restrict__ x, const float* __restrict__ proto,
    const float* __restrict__ var, const unsigned short* __restrict__ W1b,
    const float* __restrict__ b1, const unsigned short* __restrict__ W2b,
    const float* __restrict__ b2, const float* __restrict__ W3,
    const float* __restrict__ b3, const int* __restrict__ ridx,
    float* __restrict__ fsi)
{
    extern __shared__ unsigned short smem[];
    __shared__ float part[4][64];             // P3 partials (dedicated, no aliasing)
    unsigned short* bufA = smem;              // [64][256] swizzled (512 B rows)
    unsigned short* bufB = smem + 64 * 256;   // [64][256] swizzled

    const int t   = threadIdx.x;
    // XCD-chunked swizzle (bijective, 512%8==0): per-XCD x-slice ~1MB, all rules
    const int pid = blockIdx.x;
    const int lg  = (pid & 7) * 64 + (pid >> 3);
    const int kidx  = lg & 15;
    const int stile = lg >> 4;                // 0..31
    const int r     = ridx[kidx];
    const int bbase = stile * (BT * NT);

    const int wave = t >> 6, lane = t & 63;
    const int ln = lane & 15, lq = lane >> 4;
    const int sxr = (ln & 7) << 4;            // swizzle term (row&7 == ln&7)

    // row bases for A-operand (weights) fetches
    const unsigned short* W1base = W1b + (size_t)(wave * 64 + ln) * NF + lq * 8;
    const unsigned short* W2base = W2b + (size_t)(wave * 64 + ln) * NG + lq * 8;

    // rule constants, loaded ONCE per block (reused for all NT tiles)
    const int col   = (t & 63) * 4;
    const int colb  = (t & 63) * 8;
    const int rbase = t >> 6;                 // 0..3
    const float4 p4 = *(const float4*)(proto + (size_t)r * NF + col);
    float ix, iy, iz, iw;
    {
        float4 v4 = *(const float4*)(var + (size_t)r * NF + col);
        float cx = fminf(fmaxf(v4.x, 1e-4f), 0.1f);
        float cy = fminf(fmaxf(v4.y, 1e-4f), 0.1f);
        float cz = fminf(fmaxf(v4.z, 1e-4f), 0.1f);
        float cw = fminf(fmaxf(v4.w, 1e-4f), 0.1f);
        ix = 0.5f / (cx * cx); iy = 0.5f / (cy * cy);
        iz = 0.5f / (cz * cz); iw = 0.5f / (cw * cw);
    }

    // W1 chunk0/k0=0 fragments in flight before tile 0's P0
    short8 a_cur[4], a_nxt[4];
#pragma unroll
    for (int mi = 0; mi < 4; ++mi)
        a_cur[mi] = *(const short8*)(W1base + mi * 16 * NF);

    short8 b_cur[4];

    for (int it = 0; it < NT; ++it) {
        unsigned short* mv  = (it & 1) ? bufB : bufA;   // membership of tile it
        unsigned short* alt = (it & 1) ? bufA : bufB;
        const int b0 = bbase + it * BT;

        if (it == 0) {
            // standalone P0 for the first tile
#pragma unroll
            for (int i = 0; i < 16; ++i) {
                int row = i * 4 + rbase;
                p0_iter(mv, x + (size_t)(b0 + row) * NF + col, row, colb,
                        p4, ix, iy, iz, iw);
            }
            bar_lds();
        }

        float4 bi0[4];
#pragma unroll
        for (int mi = 0; mi < 4; ++mi)
            bi0[mi] = *(const float4*)(b1 + wave * 64 + mi * 16 + lq * 4);

        floatx4 acc1a[4][4], acc1b[4][4];
#pragma unroll
        for (int mi = 0; mi < 4; ++mi)
#pragma unroll
            for (int ni = 0; ni < 4; ++ni) {
                floatx4 z = {0.0f, 0.0f, 0.0f, 0.0f};
                acc1a[mi][ni] = z; acc1b[mi][ni] = z;
            }

        // ===== P1 super-region: 16 steps, no internal barrier ================
        // chunk 0 (W1 rows [0,256))
#pragma unroll
        for (int k0i = 0; k0i < 8; ++k0i) {
#pragma unroll
            for (int ni = 0; ni < 4; ++ni)
                b_cur[ni] = *(const short8*)((const char*)mv + (ni * 16 + ln) * 512
                                             + ((k0i * 64 + lq * 16) ^ sxr));
            const unsigned short* an = (k0i < 7) ? W1base + (k0i + 1) * 32
                                                 : W1base + 256 * NF;
#pragma unroll
            for (int mi = 0; mi < 4; ++mi)
                a_nxt[mi] = *(const short8*)(an + mi * 16 * NF);
#pragma unroll
            for (int ni = 0; ni < 4; ++ni)
#pragma unroll
                for (int mi = 0; mi < 4; ++mi)
                    acc1a[mi][ni] = __builtin_amdgcn_mfma_f32_16x16x32_bf16(
                        a_cur[mi], b_cur[ni], acc1a[mi][ni], 0, 0, 0);
#pragma unroll
            for (int mi = 0; mi < 4; ++mi) a_cur[mi] = a_nxt[mi];
        }
        // chunk 1 (W1 rows [256,512)) + interleaved ELU(chunk0) -> alt
#pragma unroll
        for (int k0i = 0; k0i < 8; ++k0i) {
#pragma unroll
            for (int ni = 0; ni < 4; ++ni)
                b_cur[ni] = *(const short8*)((const char*)mv + (ni * 16 + ln) * 512
                                             + ((k0i * 64 + lq * 16) ^ sxr));
            const unsigned short* an = (k0i < 7) ? W1base + 256 * NF + (k0i + 1) * 32
                                                 : W2base;
#pragma unroll
            for (int mi = 0; mi < 4; ++mi)
                a_nxt[mi] = *(const short8*)(an + mi * ((k0i < 7) ? 16 * NF : 16 * NG));
#pragma unroll
            for (int ni = 0; ni < 4; ++ni)
#pragma unroll
                for (int mi = 0; mi < 4; ++mi)
                    acc1b[mi][ni] = __builtin_amdgcn_mfma_f32_16x16x32_bf16(
                        a_cur[mi], b_cur[ni], acc1b[mi][ni], 0, 0, 0);
            if (k0i < 4)
                elu_write_row(alt, acc1a[k0i], bi0[k0i],
                              wave * 64 + k0i * 16 + lq * 4, ln, sxr);
#pragma unroll
            for (int mi = 0; mi < 4; ++mi) a_cur[mi] = a_nxt[mi];
        }
        bar_lds();   // h1 chunk0 (alt) complete; mv reads done

        float4 bi1[4];
#pragma unroll
        for (int mi = 0; mi < 4; ++mi)
            bi1[mi] = *(const float4*)(b1 + 256 + wave * 64 + mi * 16 + lq * 4);

        floatx4 acc2[4][4];
#pragma unroll
        for (int mi = 0; mi < 4; ++mi)
#pragma unroll
            for (int ni = 0; ni < 4; ++ni) {
                floatx4 z = {0.0f, 0.0f, 0.0f, 0.0f};
                acc2[mi][ni] = z;
            }

        // ===== P2 super-region ==============================================
        // chunk 0 (W2 cols [0,256)), B = alt; ELU(chunk1) -> mv's dead space
#pragma unroll
        for (int k0i = 0; k0i < 8; ++k0i) {
#pragma unroll
            for (int ni = 0; ni < 4; ++ni)
                b_cur[ni] = *(const short8*)((const char*)alt + (ni * 16 + ln) * 512
                                             + ((k0i * 64 + lq * 16) ^ sxr));
            const unsigned short* an = (k0i < 7) ? W2base + (k0i + 1) * 32
                                                 : W2base + 256;
#pragma unroll
            for (int mi = 0; mi < 4; ++mi)
                a_nxt[mi] = *(const short8*)(an + mi * 16 * NG);
#pragma unroll
            for (int ni = 0; ni < 4; ++ni)
#pragma unroll
                for (int mi = 0; mi < 4; ++mi)
                    acc2[mi][ni] = __builtin_amdgcn_mfma_f32_16x16x32_bf16(
                        a_cur[mi], b_cur[ni], acc2[mi][ni], 0, 0, 0);
            if (k0i < 4)
                elu_write_row(mv, acc1b[k0i], bi1[k0i],
                              wave * 64 + k0i * 16 + lq * 4, ln, sxr);
#pragma unroll
            for (int mi = 0; mi < 4; ++mi) a_cur[mi] = a_nxt[mi];
        }
        bar_lds();   // h1 chunk1 (mv space) complete; alt reads done -> alt free
        // chunk 1 (W2 cols [256,512)), B = mv space; interleave next tile's P0'
#pragma unroll
        for (int k0i = 0; k0i < 8; ++k0i) {
#pragma unroll
            for (int ni = 0; ni < 4; ++ni)
                b_cur[ni] = *(const short8*)((const char*)mv + (ni * 16 + ln) * 512
                                             + ((k0i * 64 + lq * 16) ^ sxr));
            const unsigned short* an = (k0i < 7) ? W2base + 256 + (k0i + 1) * 32
                                                 : W1base;   // next tile's W1 k0=0
#pragma unroll
            for (int mi = 0; mi < 4; ++mi)
                a_nxt[mi] = *(const short8*)(an + mi * ((k0i < 7) ? 16 * NG : 16 * NF));
#pragma unroll
            for (int ni = 0; ni < 4; ++ni)
#pragma unroll
                for (int mi = 0; mi < 4; ++mi)
                    acc2[mi][ni] = __builtin_amdgcn_mfma_f32_16x16x32_bf16(
                        a_cur[mi], b_cur[ni], acc2[mi][ni], 0, 0, 0);
            if (it < NT - 1) {   // next tile's membership into alt (dead buffer)
                int row0 = (2 * k0i) * 4 + rbase;
                int row1 = (2 * k0i + 1) * 4 + rbase;
                p0_iter(alt, x + (size_t)(b0 + BT + row0) * NF + col, row0, colb,
                        p4, ix, iy, iz, iw);
                p0_iter(alt, x + (size_t)(b0 + BT + row1) * NF + col, row1, colb,
                        p4, ix, iy, iz, iw);
            }
#pragma unroll
            for (int mi = 0; mi < 4; ++mi) a_cur[mi] = a_nxt[mi];
        }

        // ===== P3: fsi[b] = b3 + sum_n' ELU(h2 + b2) * W3 ====================
        float w3v[4][4], b2v[4][4];
#pragma unroll
        for (int mi = 0; mi < 4; ++mi) {
            const int np = wave * 64 + mi * 16 + lq * 4;
            const float4 wv = *(const float4*)(W3 + np);
            const float4 bv = *(const float4*)(b2 + np);
            w3v[mi][0] = wv.x; w3v[mi][1] = wv.y; w3v[mi][2] = wv.z; w3v[mi][3] = wv.w;
            b2v[mi][0] = bv.x; b2v[mi][1] = bv.y; b2v[mi][2] = bv.z; b2v[mi][3] = bv.w;
        }
#pragma unroll
        for (int ni = 0; ni < 4; ++ni) {
            float s = 0.0f;
#pragma unroll
            for (int mi = 0; mi < 4; ++mi)
#pragma unroll
                for (int rg = 0; rg < 4; ++rg)
                    s += elu1(acc2[mi][ni][rg] + b2v[mi][rg]) * w3v[mi][rg];
            s += __shfl_xor(s, 16);
            s += __shfl_xor(s, 32);
            if (lq == 0) part[wave][ni * 16 + ln] = s;
        }
        bar_lds();   // orders part[] AND the P0' writes for the next tile
        if (t < 64) {
            float s = b3[0];
#pragma unroll
            for (int w = 0; w < 4; ++w) s += part[w][t];
            fsi[(size_t)kidx * NB + b0 + t] = s;
        }
        // NOTE: next tile's P1 reads alt (written pre-barrier); ELU0' writes to
        // mv-space happen >8 MFMA steps after the barrier, safely past the
        // t<64 part[] reads (part is a dedicated static buffer anyway).
    }
}

// ---------------- kernel 2: softmax over rules + consequent + weighted sum ----
__global__ __launch_bounds__(512, 4) void cons_kernel(
    const float* __restrict__ x, const unsigned short* __restrict__ Wcb,
    const float* __restrict__ bc, const float* __restrict__ fsi,
    const int* __restrict__ ridx, float* __restrict__ outp,
    float* __restrict__ fire_out)
{
    __shared__ unsigned short xl[16 * 264];
    __shared__ float fire[16][NK];
    __shared__ float pred[4][16][16];

    const int t  = threadIdx.x;
    const int b0 = blockIdx.x * 16;

    int rr[NK];
#pragma unroll
    for (int k = 0; k < NK; ++k) rr[k] = ridx[k];

    {
        int idx = t;
#pragma unroll
        for (int i = 0; i < 2; ++i, idx += 512) {
            int row = idx >> 6, col = (idx & 63) * 4;
            const float4 xv = *(const float4*)(x + (size_t)(b0 + row) * NF + col);
            union { unsigned short s[4]; uint2 v; } pk;
            pk.s[0] = f2bf(xv.x); pk.s[1] = f2bf(xv.y);
            pk.s[2] = f2bf(xv.z); pk.s[3] = f2bf(xv.w);
            *(uint2*)(xl + row * 264 + col) = pk.v;
        }
    }
    if (t < 256) {
        const int row = t >> 4, k = t & 15;
        float v = fsi[(size_t)k * NB + b0 + row];
        float mx = v;
        mx = fmaxf(mx, __shfl_xor(mx, 1));
        mx = fmaxf(mx, __shfl_xor(mx, 2));
        mx = fmaxf(mx, __shfl_xor(mx, 4));
        mx = fmaxf(mx, __shfl_xor(mx, 8));
        float e = __expf(v - mx);
        float sum = e;
        sum += __shfl_xor(sum, 1);
        sum += __shfl_xor(sum, 2);
        sum += __shfl_xor(sum, 4);
        sum += __shfl_xor(sum, 8);
        float fv = e / sum;
        fire[row][k] = fv;
        fire_out[(size_t)b0 * NK + t] = fv;
    }
    __syncthreads();

    const int wave = t >> 6, lane = t & 63;
    const int ln = lane & 15, lq = lane >> 4;
    const int cg = wave & 3, half = wave >> 2;
    const int nb = cg * 16;

    short8 afr[8];
#pragma unroll
    for (int k0i = 0; k0i < 8; ++k0i)
        afr[k0i] = *(const short8*)(xl + ln * 264 + k0i * 32 + lq * 8);

    floatx4 oacc = {0.0f, 0.0f, 0.0f, 0.0f};
#pragma unroll
    for (int kp = 0; kp < 4; ++kp) {
        const int k0r = half * 8 + kp * 2;
        const int r0 = rr[k0r], r1 = rr[k0r + 1];
        const unsigned short* Wr0 = Wcb + ((size_t)r0 * NC + nb + ln) * NF;
        const unsigned short* Wr1 = Wcb + ((size_t)r1 * NC + nb + ln) * NF;
        floatx4 a0 = {0.0f, 0.0f, 0.0f, 0.0f};
        floatx4 a1 = {0.0f, 0.0f, 0.0f, 0.0f};
#pragma unroll
        for (int k0i = 0; k0i < 8; ++k0i) {
            short8 bb0 = *(const short8*)(Wr0 + k0i * 32 + lq * 8);
            short8 bb1 = *(const short8*)(Wr1 + k0i * 32 + lq * 8);
            a0 = __builtin_amdgcn_mfma_f32_16x16x32_bf16(afr[k0i], bb0, a0, 0, 0, 0);
            a1 = __builtin_amdgcn_mfma_f32_16x16x32_bf16(afr[k0i], bb1, a1, 0, 0, 0);
        }
        const float bias0 = bc[(size_t)r0 * NC + nb + ln];
        const float bias1 = bc[(size_t)r1 * NC + nb + ln];
#pragma unroll
        for (int rg = 0; rg < 4; ++rg) {
            const int row = lq * 4 + rg;
            oacc[rg] += fmaxf(a0[rg] + bias0, 0.0f) * fire[row][k0r]
                      + fmaxf(a1[rg] + bias1, 0.0f) * fire[row][k0r + 1];
        }
    }
    if (half == 1) {
#pragma unroll
        for (int rg = 0; rg < 4; ++rg)
            pred[cg][lq * 4 + rg][ln] = oacc[rg];
    }
    __syncthreads();
    if (half == 0) {
#pragma unroll
        for (int rg = 0; rg < 4; ++rg)
            outp[(size_t)(b0 + lq * 4 + rg) * NC + nb + ln] =
                oacc[rg] + pred[cg][lq * 4 + rg][ln];
    }
}

extern "C" void kernel_launch(void* const* d_in, const int* in_sizes, int n_in,
                              void* d_out, int out_size, void* d_ws, size_t ws_size,
                              hipStream_t stream)
{
    (void)in_sizes; (void)n_in; (void)out_size;
    if (ws_size < 2097152) return;

    const float* x     = (const float*)d_in[0];
    const float* proto = (const float*)d_in[1];
    const float* var   = (const float*)d_in[2];
    const float* W1    = (const float*)d_in[3];
    const float* b1    = (const float*)d_in[4];
    const float* W2    = (const float*)d_in[5];
    const float* b2    = (const float*)d_in[6];
    const float* W3    = (const float*)d_in[7];
    const float* b3    = (const float*)d_in[8];
    const float* Wc    = (const float*)d_in[9];
    const float* bc    = (const float*)d_in[10];
    const int*   ridx  = (const int*)d_in[11];

    unsigned short* wb  = (unsigned short*)d_ws;
    unsigned short* W1b = wb;                 // 131072
    unsigned short* W2b = wb + 131072;        // 131072
    unsigned short* Wcb = wb + 262144;        // 524288
    float* fsi = (float*)((char*)d_ws + (size_t)786432 * 2);

    float* outp     = (float*)d_out;
    float* fire_out = outp + (size_t)NB * NC;

    conv_kernel<<<3072, 256, 0, stream>>>(W1, W2, Wc, wb);

    const int fs_lds = 2 * 64 * 256 * 2;  // 65536 B dynamic (+1KB static part[])
    hipFuncSetAttribute((const void*)fs_kernel,
                        hipFuncAttributeMaxDynamicSharedMemorySize, fs_lds);
    fs_kernel<<<512, 256, fs_lds, stream>>>(x, proto, var, W1b, b1, W2b, b2,
                                            W3, b3, ridx, fsi);
    cons_kernel<<<512, 512, 0, stream>>>(x, Wcb, bc, fsi, ridx, outp, fire_out);
}

// Round 9
// 254.400 us; speedup vs baseline: 1.3945x; 1.3945x over previous
//
#include <hip/hip_runtime.h>
#include <cstdint>
#include <cstddef>

#define NF 256   // features
#define NG 512   // hidden (2F)
#define NC 64    // classes
#define NB 8192  // batch
#define NK 16    // active rules
#define BT 64    // fs batch tile

typedef __attribute__((ext_vector_type(8))) short short8;
typedef __attribute__((ext_vector_type(4))) float floatx4;

__device__ __forceinline__ unsigned short f2bf(float f) {
    union { float f; unsigned int u; } a; a.f = f;
    unsigned int u = a.u;
    u += 0x7fffu + ((u >> 16) & 1u);   // RNE
    return (unsigned short)(u >> 16);
}
__device__ __forceinline__ float elu1(float z) {
    return z > 0.0f ? z : (__expf(z) - 1.0f);
}

// LDS-only barrier: orders ds ops across the workgroup WITHOUT draining vmcnt.
__device__ __forceinline__ void bar_lds() {
    __builtin_amdgcn_sched_barrier(0);
    asm volatile("s_waitcnt lgkmcnt(0)" ::: "memory");
    __builtin_amdgcn_s_barrier();
    __builtin_amdgcn_sched_barrier(0);
}

// ---------------- kernel 0: weights fp32 -> bf16 in workspace ----------------
__global__ __launch_bounds__(256) void conv_kernel(
    const float* __restrict__ W1, const float* __restrict__ W2,
    const float* __restrict__ Wc, unsigned short* __restrict__ wb)
{
    int i = blockIdx.x * 256 + threadIdx.x;
    if (i < 131072)       wb[i] = f2bf(W1[i]);
    else if (i < 262144)  wb[i] = f2bf(W2[i - 131072]);
    else if (i < 786432)  wb[i] = f2bf(Wc[i - 262144]);
}

// ---------------- kernel 1: fused membership -> MLP -> fsi (compact code) ----
// grid: 2048 blocks = 16 rules x 128 batch tiles; 256 threads (4 waves).
// SAME math/FP-order as the 150us R4/R6 kernels (alternating chunk structure),
// but with ROLLED loops: chunk loop unroll 1, k-loops unroll 2, P0 unroll 4.
// Body shrinks ~30-40KB -> ~5KB so it stays I$-resident: theory is that the
// invariant-to-everything 150us plateau is instruction-fetch starvation from
// streaming a fully-unrolled body once per block (8 blocks/CU, co-resident
// blocks at distant PCs). Only the tiny mi/ni loops stay unrolled (static
// acc indexing, rule #20). acc footprint 128 regs (acc1+acc2) -> no spills.
__global__ __launch_bounds__(256, 2) void fs_kernel(
    const float* __restrict__ x, const float* __restrict__ proto,
    const float* __restrict__ var, const unsigned short* __restrict__ W1b,
    const float* __restrict__ b1, const unsigned short* __restrict__ W2b,
    const float* __restrict__ b2, const float* __restrict__ W3,
    const float* __restrict__ b3, const int* __restrict__ ridx,
    float* __restrict__ fsi)
{
    extern __shared__ unsigned short smem[];
    __shared__ float part[4][64];
    unsigned short* mv   = smem;              // [64][256] swizzled (512 B rows)
    unsigned short* cbuf = smem + 64 * 256;   // [64][256] swizzled, reused per chunk

    const int t   = threadIdx.x;
    // XCD-chunked swizzle (bijective, 2048%8==0); keeps x/weights L2-resident
    const int pid = blockIdx.x;
    const int lg  = (pid & 7) * 256 + (pid >> 3);
    const int kidx = lg & 15;
    const int tile = lg >> 4;
    const int r    = ridx[kidx];
    const int b0   = tile * BT;

    const int wave = t >> 6, lane = t & 63;
    const int ln = lane & 15, lq = lane >> 4;
    const int sxr = (ln & 7) << 4;            // swizzle term (row&7 == ln&7)

    // ---- P0: membership mv = exp(-(x-p)^2/(2 v^2)), v=clip(var,1e-4,0.1) ----
    {
        const int col   = (t & 63) * 4;
        const int colb  = (t & 63) * 8;
        const int rbase = t >> 6;             // 0..3
        const float4 p4 = *(const float4*)(proto + (size_t)r * NF + col);
        float4 v4 = *(const float4*)(var + (size_t)r * NF + col);
        float cx = fminf(fmaxf(v4.x, 1e-4f), 0.1f);
        float cy = fminf(fmaxf(v4.y, 1e-4f), 0.1f);
        float cz = fminf(fmaxf(v4.z, 1e-4f), 0.1f);
        float cw = fminf(fmaxf(v4.w, 1e-4f), 0.1f);
        float ix = 0.5f / (cx * cx), iy = 0.5f / (cy * cy);
        float iz = 0.5f / (cz * cz), iw = 0.5f / (cw * cw);
#pragma unroll 4
        for (int i = 0; i < 16; ++i) {
            int row = i * 4 + rbase;
            const float4 xv = *(const float4*)(x + (size_t)(b0 + row) * NF + col);
            float dx = xv.x - p4.x, dy = xv.y - p4.y, dz = xv.z - p4.z, dw = xv.w - p4.w;
            union { unsigned short s[4]; uint2 v; } pk;
            pk.s[0] = f2bf(__expf(-dx * dx * ix));
            pk.s[1] = f2bf(__expf(-dy * dy * iy));
            pk.s[2] = f2bf(__expf(-dz * dz * iz));
            pk.s[3] = f2bf(__expf(-dw * dw * iw));
            *(uint2*)((char*)mv + row * 512 + (colb ^ ((row & 7) << 4))) = pk.v;
        }
    }
    bar_lds();

    // persistent h2 accumulator: n' = wave*64 + mi*16 + lq*4 + rg, b = ni*16 + ln
    floatx4 acc2[4][4];
#pragma unroll
    for (int mi = 0; mi < 4; ++mi)
#pragma unroll
        for (int ni = 0; ni < 4; ++ni) {
            floatx4 z = {0.0f, 0.0f, 0.0f, 0.0f};
            acc2[mi][ni] = z;
        }

#pragma unroll 1
    for (int c = 0; c < 2; ++c) {
        // ---- P1 chunk c: h1^T for n in [c*256, c*256+256) ----
        floatx4 acc1[4][4];
#pragma unroll
        for (int mi = 0; mi < 4; ++mi)
#pragma unroll
            for (int ni = 0; ni < 4; ++ni) {
                floatx4 z = {0.0f, 0.0f, 0.0f, 0.0f};
                acc1[mi][ni] = z;
            }
#pragma unroll 2
        for (int k0i = 0; k0i < 8; ++k0i) {
            short8 a[4], b[4];
#pragma unroll
            for (int mi = 0; mi < 4; ++mi)
                a[mi] = *(const short8*)(W1b
                        + (size_t)(c * 256 + wave * 64 + mi * 16 + ln) * NF
                        + k0i * 32 + lq * 8);
#pragma unroll
            for (int ni = 0; ni < 4; ++ni)
                b[ni] = *(const short8*)((const char*)mv + (ni * 16 + ln) * 512
                                         + ((k0i * 64 + lq * 16) ^ sxr));
#pragma unroll
            for (int ni = 0; ni < 4; ++ni)
#pragma unroll
                for (int mi = 0; mi < 4; ++mi)
                    acc1[mi][ni] = __builtin_amdgcn_mfma_f32_16x16x32_bf16(
                        a[mi], b[ni], acc1[mi][ni], 0, 0, 0);
        }
        bar_lds();   // prior chunk's P2 reads of cbuf are done
        // ---- ELU + bias -> cbuf (swizzled; 4 consecutive n per lane) ----
#pragma unroll
        for (int mi = 0; mi < 4; ++mi) {
            const int nl = wave * 64 + mi * 16 + lq * 4;   // chunk-local n
            const float4 b4 = *(const float4*)(b1 + c * 256 + nl);
#pragma unroll
            for (int ni = 0; ni < 4; ++ni) {
                union { unsigned short us[4]; uint2 v; } pk;
                pk.us[0] = f2bf(elu1(acc1[mi][ni][0] + b4.x));
                pk.us[1] = f2bf(elu1(acc1[mi][ni][1] + b4.y));
                pk.us[2] = f2bf(elu1(acc1[mi][ni][2] + b4.z));
                pk.us[3] = f2bf(elu1(acc1[mi][ni][3] + b4.w));
                *(uint2*)((char*)cbuf + (ni * 16 + ln) * 512 + ((nl * 2) ^ sxr)) = pk.v;
            }
        }
        bar_lds();
        // ---- P2 chunk c: acc2 += W2[:, c*256:+256] @ h1_c^T ----
#pragma unroll 2
        for (int k0i = 0; k0i < 8; ++k0i) {
            short8 a[4], b[4];
#pragma unroll
            for (int mi = 0; mi < 4; ++mi)
                a[mi] = *(const short8*)(W2b
                        + (size_t)(wave * 64 + mi * 16 + ln) * NG
                        + c * 256 + k0i * 32 + lq * 8);
#pragma unroll
            for (int ni = 0; ni < 4; ++ni)
                b[ni] = *(const short8*)((const char*)cbuf + (ni * 16 + ln) * 512
                                         + ((k0i * 64 + lq * 16) ^ sxr));
#pragma unroll
            for (int ni = 0; ni < 4; ++ni)
#pragma unroll
                for (int mi = 0; mi < 4; ++mi)
                    acc2[mi][ni] = __builtin_amdgcn_mfma_f32_16x16x32_bf16(
                        a[mi], b[ni], acc2[mi][ni], 0, 0, 0);
        }
    }

    // ---- P3: fsi[b] = b3 + sum_n' ELU(h2[b][n'] + b2) * W3[n'] ----
    float w3v[4][4], b2v[4][4];
#pragma unroll
    for (int mi = 0; mi < 4; ++mi) {
        const int np = wave * 64 + mi * 16 + lq * 4;
        const float4 wv = *(const float4*)(W3 + np);
        const float4 bv = *(const float4*)(b2 + np);
        w3v[mi][0] = wv.x; w3v[mi][1] = wv.y; w3v[mi][2] = wv.z; w3v[mi][3] = wv.w;
        b2v[mi][0] = bv.x; b2v[mi][1] = bv.y; b2v[mi][2] = bv.z; b2v[mi][3] = bv.w;
    }
#pragma unroll
    for (int ni = 0; ni < 4; ++ni) {
        float s = 0.0f;
#pragma unroll
        for (int mi = 0; mi < 4; ++mi)
#pragma unroll
            for (int rg = 0; rg < 4; ++rg)
                s += elu1(acc2[mi][ni][rg] + b2v[mi][rg]) * w3v[mi][rg];
        s += __shfl_xor(s, 16);
        s += __shfl_xor(s, 32);
        if (lq == 0) part[wave][ni * 16 + ln] = s;
    }
    bar_lds();
    if (t < 64) {
        float s = b3[0];
#pragma unroll
        for (int w = 0; w < 4; ++w) s += part[w][t];
        fsi[(size_t)kidx * NB + b0 + t] = s;
    }
}

// ---------------- kernel 2: softmax over rules + consequent + weighted sum ----
__global__ __launch_bounds__(512, 4) void cons_kernel(
    const float* __restrict__ x, const unsigned short* __restrict__ Wcb,
    const float* __restrict__ bc, const float* __restrict__ fsi,
    const int* __restrict__ ridx, float* __restrict__ outp,
    float* __restrict__ fire_out)
{
    __shared__ unsigned short xl[16 * 264];
    __shared__ float fire[16][NK];
    __shared__ float pred[4][16][16];

    const int t  = threadIdx.x;
    const int b0 = blockIdx.x * 16;

    int rr[NK];
#pragma unroll
    for (int k = 0; k < NK; ++k) rr[k] = ridx[k];

    {
        int idx = t;
#pragma unroll
        for (int i = 0; i < 2; ++i, idx += 512) {
            int row = idx >> 6, col = (idx & 63) * 4;
            const float4 xv = *(const float4*)(x + (size_t)(b0 + row) * NF + col);
            union { unsigned short s[4]; uint2 v; } pk;
            pk.s[0] = f2bf(xv.x); pk.s[1] = f2bf(xv.y);
            pk.s[2] = f2bf(xv.z); pk.s[3] = f2bf(xv.w);
            *(uint2*)(xl + row * 264 + col) = pk.v;
        }
    }
    if (t < 256) {
        const int row = t >> 4, k = t & 15;
        float v = fsi[(size_t)k * NB + b0 + row];
        float mx = v;
        mx = fmaxf(mx, __shfl_xor(mx, 1));
        mx = fmaxf(mx, __shfl_xor(mx, 2));
        mx = fmaxf(mx, __shfl_xor(mx, 4));
        mx = fmaxf(mx, __shfl_xor(mx, 8));
        float e = __expf(v - mx);
        float sum = e;
        sum += __shfl_xor(sum, 1);
        sum += __shfl_xor(sum, 2);
        sum += __shfl_xor(sum, 4);
        sum += __shfl_xor(sum, 8);
        float fv = e / sum;
        fire[row][k] = fv;
        fire_out[(size_t)b0 * NK + t] = fv;
    }
    __syncthreads();

    const int wave = t >> 6, lane = t & 63;
    const int ln = lane & 15, lq = lane >> 4;
    const int cg = wave & 3, half = wave >> 2;
    const int nb = cg * 16;

    short8 afr[8];
#pragma unroll
    for (int k0i = 0; k0i < 8; ++k0i)
        afr[k0i] = *(const short8*)(xl + ln * 264 + k0i * 32 + lq * 8);

    floatx4 oacc = {0.0f, 0.0f, 0.0f, 0.0f};
#pragma unroll
    for (int kp = 0; kp < 4; ++kp) {
        const int k0r = half * 8 + kp * 2;
        const int r0 = rr[k0r], r1 = rr[k0r + 1];
        const unsigned short* Wr0 = Wcb + ((size_t)r0 * NC + nb + ln) * NF;
        const unsigned short* Wr1 = Wcb + ((size_t)r1 * NC + nb + ln) * NF;
        floatx4 a0 = {0.0f, 0.0f, 0.0f, 0.0f};
        floatx4 a1 = {0.0f, 0.0f, 0.0f, 0.0f};
#pragma unroll
        for (int k0i = 0; k0i < 8; ++k0i) {
            short8 bb0 = *(const short8*)(Wr0 + k0i * 32 + lq * 8);
            short8 bb1 = *(const short8*)(Wr1 + k0i * 32 + lq * 8);
            a0 = __builtin_amdgcn_mfma_f32_16x16x32_bf16(afr[k0i], bb0, a0, 0, 0, 0);
            a1 = __builtin_amdgcn_mfma_f32_16x16x32_bf16(afr[k0i], bb1, a1, 0, 0, 0);
        }
        const float bias0 = bc[(size_t)r0 * NC + nb + ln];
        const float bias1 = bc[(size_t)r1 * NC + nb + ln];
#pragma unroll
        for (int rg = 0; rg < 4; ++rg) {
            const int row = lq * 4 + rg;
            oacc[rg] += fmaxf(a0[rg] + bias0, 0.0f) * fire[row][k0r]
                      + fmaxf(a1[rg] + bias1, 0.0f) * fire[row][k0r + 1];
        }
    }
    if (half == 1) {
#pragma unroll
        for (int rg = 0; rg < 4; ++rg)
            pred[cg][lq * 4 + rg][ln] = oacc[rg];
    }
    __syncthreads();
    if (half == 0) {
#pragma unroll
        for (int rg = 0; rg < 4; ++rg)
            outp[(size_t)(b0 + lq * 4 + rg) * NC + nb + ln] =
                oacc[rg] + pred[cg][lq * 4 + rg][ln];
    }
}

extern "C" void kernel_launch(void* const* d_in, const int* in_sizes, int n_in,
                              void* d_out, int out_size, void* d_ws, size_t ws_size,
                              hipStream_t stream)
{
    (void)in_sizes; (void)n_in; (void)out_size;
    if (ws_size < 2097152) return;

    const float* x     = (const float*)d_in[0];
    const float* proto = (const float*)d_in[1];
    const float* var   = (const float*)d_in[2];
    const float* W1    = (const float*)d_in[3];
    const float* b1    = (const float*)d_in[4];
    const float* W2    = (const float*)d_in[5];
    const float* b2    = (const float*)d_in[6];
    const float* W3    = (const float*)d_in[7];
    const float* b3    = (const float*)d_in[8];
    const float* Wc    = (const float*)d_in[9];
    const float* bc    = (const float*)d_in[10];
    const int*   ridx  = (const int*)d_in[11];

    unsigned short* wb  = (unsigned short*)d_ws;
    unsigned short* W1b = wb;                 // 131072
    unsigned short* W2b = wb + 131072;        // 131072
    unsigned short* Wcb = wb + 262144;        // 524288
    float* fsi = (float*)((char*)d_ws + (size_t)786432 * 2);

    float* outp     = (float*)d_out;
    float* fire_out = outp + (size_t)NB * NC;

    conv_kernel<<<3072, 256, 0, stream>>>(W1, W2, Wc, wb);

    const int fs_lds = 2 * 64 * 256 * 2;  // 65536 B dynamic (+1KB static part[])
    hipFuncSetAttribute((const void*)fs_kernel,
                        hipFuncAttributeMaxDynamicSharedMemorySize, fs_lds);
    fs_kernel<<<2048, 256, fs_lds, stream>>>(x, proto, var, W1b, b1, W2b, b2,
                                             W3, b3, ridx, fsi);
    cons_kernel<<<512, 512, 0, stream>>>(x, Wcb, bc, fsi, ridx, outp, fire_out);
}

// Round 10
// 192.305 us; speedup vs baseline: 1.8448x; 1.3229x over previous
//
#include <hip/hip_runtime.h>
#include <hip/hip_bf16.h>
#include <cstdint>
#include <cstddef>

#define NF 256   // features
#define NG 512   // hidden (2F)
#define NC 64    // classes
#define NB 8192  // batch
#define NK 16    // active rules
#define BT 64    // fs batch tile

typedef __attribute__((ext_vector_type(8))) short short8;
typedef __attribute__((ext_vector_type(4))) float floatx4;

__device__ __forceinline__ unsigned short f2bf(float f) {
    union { float f; unsigned int u; } a; a.f = f;
    unsigned int u = a.u;
    u += 0x7fffu + ((u >> 16) & 1u);   // RNE
    return (unsigned short)(u >> 16);
}
__device__ __forceinline__ float elu1(float z) {
    return z > 0.0f ? z : (__expf(z) - 1.0f);
}
// HW-packed f32x2 -> bf16x2 (v_cvt_pk_bf16_f32, RNE — bit-identical to f2bf)
__device__ __forceinline__ unsigned int pk2bf(float a, float b) {
    __hip_bfloat162 h = __float22bfloat162_rn(make_float2(a, b));
    union { __hip_bfloat162 h; unsigned int u; } cv; cv.h = h; return cv.u;
}

// LDS-only barrier: orders ds ops across the workgroup WITHOUT draining vmcnt.
__device__ __forceinline__ void bar_lds() {
    __builtin_amdgcn_sched_barrier(0);
    asm volatile("s_waitcnt lgkmcnt(0)" ::: "memory");
    __builtin_amdgcn_s_barrier();
    __builtin_amdgcn_sched_barrier(0);
}

// ---------------- kernel 0: weights fp32 -> bf16, FRAGMENT-TRANSPOSED --------
// W1t/W2t are stored in MFMA-fragment order: fragment (N-block, K-block) is a
// contiguous 1024 B run, element ((N*KB + K)*64 + lane)*8 + e  maps to
// W[(N*16 + (lane&15))*LD + K*32 + (lane>>4)*8 + e].  fs A-loads then become
// base + immediate-offset + lane*16B: zero per-step address VALU, fully
// contiguous 1KB/instruction (fewer, wider L2 requests).  Same f2bf bits as
// all prior rounds -> FP-identical results.  Wcb layout unchanged (cons).
__global__ __launch_bounds__(256) void conv_kernel(
    const float* __restrict__ W1, const float* __restrict__ W2,
    const float* __restrict__ Wc, unsigned short* __restrict__ wb)
{
    int i = blockIdx.x * 256 + threadIdx.x;
    if (i < 131072) {            // W1t: 32 N-blocks x 8 K-blocks
        int e = i & 7, l = (i >> 3) & 63, K = (i >> 9) & 7, N = i >> 12;
        int src = (N * 16 + (l & 15)) * NF + K * 32 + (l >> 4) * 8 + e;
        wb[i] = f2bf(W1[src]);
    } else if (i < 262144) {     // W2t: 16 N-blocks x 16 K-blocks
        int o = i - 131072;
        int e = o & 7, l = (o >> 3) & 63, K = (o >> 9) & 15, N = o >> 13;
        int src = (N * 16 + (l & 15)) * NG + K * 32 + (l >> 4) * 8 + e;
        wb[i] = f2bf(W2[src]);
    } else if (i < 786432) {
        wb[i] = f2bf(Wc[i - 262144]);
    }
}

// ---------------- kernel 1: fused membership -> MLP -> fsi -------------------
// R9 structure (rolled loops, swizzled LDS, XCD swizzle, bar_lds) with the
// instruction-bill cuts: fragment-contiguous weight loads (no addr VALU),
// v_cvt_pk_bf16_f32 packing (P0 + ELU), exp2-folded membership constants.
__global__ __launch_bounds__(256, 2) void fs_kernel(
    const float* __restrict__ x, const float* __restrict__ proto,
    const float* __restrict__ var, const unsigned short* __restrict__ W1b,
    const float* __restrict__ b1, const unsigned short* __restrict__ W2b,
    const float* __restrict__ b2, const float* __restrict__ W3,
    const float* __restrict__ b3, const int* __restrict__ ridx,
    float* __restrict__ fsi)
{
    extern __shared__ unsigned short smem[];
    __shared__ float part[4][64];
    unsigned short* mv   = smem;              // [64][256] swizzled (512 B rows)
    unsigned short* cbuf = smem + 64 * 256;   // [64][256] swizzled, reused per chunk

    const int t   = threadIdx.x;
    // XCD-chunked swizzle (bijective, 2048%8==0); keeps x/weights L2-resident
    const int pid = blockIdx.x;
    const int lg  = (pid & 7) * 256 + (pid >> 3);
    const int kidx = lg & 15;
    const int tile = lg >> 4;
    const int r    = ridx[kidx];
    const int b0   = tile * BT;

    const int wave = t >> 6, lane = t & 63;
    const int ln = lane & 15, lq = lane >> 4;
    const int sxr = (ln & 7) << 4;            // swizzle term (row&7 == ln&7)

    // ---- P0: membership mv = exp(-(x-p)^2/(2 v^2)), v=clip(var,1e-4,0.1) ----
    {
        const int col   = (t & 63) * 4;
        const int colb  = (t & 63) * 8;
        const int rbase = t >> 6;             // 0..3
        const float4 p4 = *(const float4*)(proto + (size_t)r * NF + col);
        float4 v4 = *(const float4*)(var + (size_t)r * NF + col);
        float cx = fminf(fmaxf(v4.x, 1e-4f), 0.1f);
        float cy = fminf(fmaxf(v4.y, 1e-4f), 0.1f);
        float cz = fminf(fmaxf(v4.z, 1e-4f), 0.1f);
        float cw = fminf(fmaxf(v4.w, 1e-4f), 0.1f);
        const float L2E = 1.44269504088896340736f;   // fold log2e: __expf(z)
        float ix = (0.5f * L2E) / (cx * cx);         // == exp2(z*log2e)
        float iy = (0.5f * L2E) / (cy * cy);
        float iz = (0.5f * L2E) / (cz * cz);
        float iw = (0.5f * L2E) / (cw * cw);
#pragma unroll 4
        for (int i = 0; i < 16; ++i) {
            int row = i * 4 + rbase;
            const float4 xv = *(const float4*)(x + (size_t)(b0 + row) * NF + col);
            float dx = xv.x - p4.x, dy = xv.y - p4.y, dz = xv.z - p4.z, dw = xv.w - p4.w;
            uint2 pk;
            pk.x = pk2bf(exp2f(-dx * dx * ix), exp2f(-dy * dy * iy));
            pk.y = pk2bf(exp2f(-dz * dz * iz), exp2f(-dw * dw * iw));
            *(uint2*)((char*)mv + row * 512 + (colb ^ ((row & 7) << 4))) = pk;
        }
    }
    bar_lds();

    // persistent h2 accumulator: n' = wave*64 + mi*16 + lq*4 + rg, b = ni*16 + ln
    floatx4 acc2[4][4];
#pragma unroll
    for (int mi = 0; mi < 4; ++mi)
#pragma unroll
        for (int ni = 0; ni < 4; ++ni) {
            floatx4 z = {0.0f, 0.0f, 0.0f, 0.0f};
            acc2[mi][ni] = z;
        }

#pragma unroll 1
    for (int c = 0; c < 2; ++c) {
        // ---- P1 chunk c: h1^T for n in [c*256, c*256+256) ----
        // A-frags: W1t fragment (N = c*16+wave*4+mi, K = k0i), contiguous.
        floatx4 acc1[4][4];
#pragma unroll
        for (int mi = 0; mi < 4; ++mi)
#pragma unroll
            for (int ni = 0; ni < 4; ++ni) {
                floatx4 z = {0.0f, 0.0f, 0.0f, 0.0f};
                acc1[mi][ni] = z;
            }
        const unsigned short* w1p = W1b + c * 65536 + wave * 16384 + lane * 8;
#pragma unroll 2
        for (int k0i = 0; k0i < 8; ++k0i) {
            short8 a[4], b[4];
#pragma unroll
            for (int mi = 0; mi < 4; ++mi)
                a[mi] = *(const short8*)(w1p + mi * 4096 + k0i * 512);
#pragma unroll
            for (int ni = 0; ni < 4; ++ni)
                b[ni] = *(const short8*)((const char*)mv + (ni * 16 + ln) * 512
                                         + ((k0i * 64 + lq * 16) ^ sxr));
#pragma unroll
            for (int ni = 0; ni < 4; ++ni)
#pragma unroll
                for (int mi = 0; mi < 4; ++mi)
                    acc1[mi][ni] = __builtin_amdgcn_mfma_f32_16x16x32_bf16(
                        a[mi], b[ni], acc1[mi][ni], 0, 0, 0);
        }
        bar_lds();   // prior chunk's P2 reads of cbuf are done
        // ---- ELU + bias -> cbuf (swizzled; 4 consecutive n per lane) ----
#pragma unroll
        for (int mi = 0; mi < 4; ++mi) {
            const int nl = wave * 64 + mi * 16 + lq * 4;   // chunk-local n
            const float4 b4 = *(const float4*)(b1 + c * 256 + nl);
#pragma unroll
            for (int ni = 0; ni < 4; ++ni) {
                uint2 pk;
                pk.x = pk2bf(elu1(acc1[mi][ni][0] + b4.x),
                             elu1(acc1[mi][ni][1] + b4.y));
                pk.y = pk2bf(elu1(acc1[mi][ni][2] + b4.z),
                             elu1(acc1[mi][ni][3] + b4.w));
                *(uint2*)((char*)cbuf + (ni * 16 + ln) * 512 + ((nl * 2) ^ sxr)) = pk;
            }
        }
        bar_lds();
        // ---- P2 chunk c: acc2 += W2[:, c*256:+256] @ h1_c^T ----
        // A-frags: W2t fragment (N = wave*4+mi, K = c*8+k0i), contiguous.
        const unsigned short* w2p = W2b + wave * 32768 + c * 8 * 512 + lane * 8;
#pragma unroll 2
        for (int k0i = 0; k0i < 8; ++k0i) {
            short8 a[4], b[4];
#pragma unroll
            for (int mi = 0; mi < 4; ++mi)
                a[mi] = *(const short8*)(w2p + mi * 8192 + k0i * 512);
#pragma unroll
            for (int ni = 0; ni < 4; ++ni)
                b[ni] = *(const short8*)((const char*)cbuf + (ni * 16 + ln) * 512
                                         + ((k0i * 64 + lq * 16) ^ sxr));
#pragma unroll
            for (int ni = 0; ni < 4; ++ni)
#pragma unroll
                for (int mi = 0; mi < 4; ++mi)
                    acc2[mi][ni] = __builtin_amdgcn_mfma_f32_16x16x32_bf16(
                        a[mi], b[ni], acc2[mi][ni], 0, 0, 0);
        }
    }

    // ---- P3: fsi[b] = b3 + sum_n' ELU(h2[b][n'] + b2) * W3[n'] ----
    float w3v[4][4], b2v[4][4];
#pragma unroll
    for (int mi = 0; mi < 4; ++mi) {
        const int np = wave * 64 + mi * 16 + lq * 4;
        const float4 wv = *(const float4*)(W3 + np);
        const float4 bv = *(const float4*)(b2 + np);
        w3v[mi][0] = wv.x; w3v[mi][1] = wv.y; w3v[mi][2] = wv.z; w3v[mi][3] = wv.w;
        b2v[mi][0] = bv.x; b2v[mi][1] = bv.y; b2v[mi][2] = bv.z; b2v[mi][3] = bv.w;
    }
#pragma unroll
    for (int ni = 0; ni < 4; ++ni) {
        float s = 0.0f;
#pragma unroll
        for (int mi = 0; mi < 4; ++mi)
#pragma unroll
            for (int rg = 0; rg < 4; ++rg)
                s += elu1(acc2[mi][ni][rg] + b2v[mi][rg]) * w3v[mi][rg];
        s += __shfl_xor(s, 16);
        s += __shfl_xor(s, 32);
        if (lq == 0) part[wave][ni * 16 + ln] = s;
    }
    bar_lds();
    if (t < 64) {
        float s = b3[0];
#pragma unroll
        for (int w = 0; w < 4; ++w) s += part[w][t];
        fsi[(size_t)kidx * NB + b0 + t] = s;
    }
}

// ---------------- kernel 2: softmax over rules + consequent + weighted sum ----
__global__ __launch_bounds__(512, 4) void cons_kernel(
    const float* __restrict__ x, const unsigned short* __restrict__ Wcb,
    const float* __restrict__ bc, const float* __restrict__ fsi,
    const int* __restrict__ ridx, float* __restrict__ outp,
    float* __restrict__ fire_out)
{
    __shared__ unsigned short xl[16 * 264];
    __shared__ float fire[16][NK];
    __shared__ float pred[4][16][16];

    const int t  = threadIdx.x;
    const int b0 = blockIdx.x * 16;

    int rr[NK];
#pragma unroll
    for (int k = 0; k < NK; ++k) rr[k] = ridx[k];

    {
        int idx = t;
#pragma unroll
        for (int i = 0; i < 2; ++i, idx += 512) {
            int row = idx >> 6, col = (idx & 63) * 4;
            const float4 xv = *(const float4*)(x + (size_t)(b0 + row) * NF + col);
            uint2 pk;
            pk.x = pk2bf(xv.x, xv.y);
            pk.y = pk2bf(xv.z, xv.w);
            *(uint2*)(xl + row * 264 + col) = pk;
        }
    }
    if (t < 256) {
        const int row = t >> 4, k = t & 15;
        float v = fsi[(size_t)k * NB + b0 + row];
        float mx = v;
        mx = fmaxf(mx, __shfl_xor(mx, 1));
        mx = fmaxf(mx, __shfl_xor(mx, 2));
        mx = fmaxf(mx, __shfl_xor(mx, 4));
        mx = fmaxf(mx, __shfl_xor(mx, 8));
        float e = __expf(v - mx);
        float sum = e;
        sum += __shfl_xor(sum, 1);
        sum += __shfl_xor(sum, 2);
        sum += __shfl_xor(sum, 4);
        sum += __shfl_xor(sum, 8);
        float fv = e / sum;
        fire[row][k] = fv;
        fire_out[(size_t)b0 * NK + t] = fv;
    }
    __syncthreads();

    const int wave = t >> 6, lane = t & 63;
    const int ln = lane & 15, lq = lane >> 4;
    const int cg = wave & 3, half = wave >> 2;
    const int nb = cg * 16;

    short8 afr[8];
#pragma unroll
    for (int k0i = 0; k0i < 8; ++k0i)
        afr[k0i] = *(const short8*)(xl + ln * 264 + k0i * 32 + lq * 8);

    floatx4 oacc = {0.0f, 0.0f, 0.0f, 0.0f};
#pragma unroll
    for (int kp = 0; kp < 4; ++kp) {
        const int k0r = half * 8 + kp * 2;
        const int r0 = rr[k0r], r1 = rr[k0r + 1];
        const unsigned short* Wr0 = Wcb + ((size_t)r0 * NC + nb + ln) * NF;
        const unsigned short* Wr1 = Wcb + ((size_t)r1 * NC + nb + ln) * NF;
        floatx4 a0 = {0.0f, 0.0f, 0.0f, 0.0f};
        floatx4 a1 = {0.0f, 0.0f, 0.0f, 0.0f};
#pragma unroll
        for (int k0i = 0; k0i < 8; ++k0i) {
            short8 bb0 = *(const short8*)(Wr0 + k0i * 32 + lq * 8);
            short8 bb1 = *(const short8*)(Wr1 + k0i * 32 + lq * 8);
            a0 = __builtin_amdgcn_mfma_f32_16x16x32_bf16(afr[k0i], bb0, a0, 0, 0, 0);
            a1 = __builtin_amdgcn_mfma_f32_16x16x32_bf16(afr[k0i], bb1, a1, 0, 0, 0);
        }
        const float bias0 = bc[(size_t)r0 * NC + nb + ln];
        const float bias1 = bc[(size_t)r1 * NC + nb + ln];
#pragma unroll
        for (int rg = 0; rg < 4; ++rg) {
            const int row = lq * 4 + rg;
            oacc[rg] += fmaxf(a0[rg] + bias0, 0.0f) * fire[row][k0r]
                      + fmaxf(a1[rg] + bias1, 0.0f) * fire[row][k0r + 1];
        }
    }
    if (half == 1) {
#pragma unroll
        for (int rg = 0; rg < 4; ++rg)
            pred[cg][lq * 4 + rg][ln] = oacc[rg];
    }
    __syncthreads();
    if (half == 0) {
#pragma unroll
        for (int rg = 0; rg < 4; ++rg)
            outp[(size_t)(b0 + lq * 4 + rg) * NC + nb + ln] =
                oacc[rg] + pred[cg][lq * 4 + rg][ln];
    }
}

extern "C" void kernel_launch(void* const* d_in, const int* in_sizes, int n_in,
                              void* d_out, int out_size, void* d_ws, size_t ws_size,
                              hipStream_t stream)
{
    (void)in_sizes; (void)n_in; (void)out_size;
    if (ws_size < 2097152) return;

    const float* x     = (const float*)d_in[0];
    const float* proto = (const float*)d_in[1];
    const float* var   = (const float*)d_in[2];
    const float* W1    = (const float*)d_in[3];
    const float* b1    = (const float*)d_in[4];
    const float* W2    = (const float*)d_in[5];
    const float* b2    = (const float*)d_in[6];
    const float* W3    = (const float*)d_in[7];
    const float* b3    = (const float*)d_in[8];
    const float* Wc    = (const float*)d_in[9];
    const float* bc    = (const float*)d_in[10];
    const int*   ridx  = (const int*)d_in[11];

    unsigned short* wb  = (unsigned short*)d_ws;
    unsigned short* W1b = wb;                 // 131072 (fragment-transposed)
    unsigned short* W2b = wb + 131072;        // 131072 (fragment-transposed)
    unsigned short* Wcb = wb + 262144;        // 524288 (row-major, for cons)
    float* fsi = (float*)((char*)d_ws + (size_t)786432 * 2);

    float* outp     = (float*)d_out;
    float* fire_out = outp + (size_t)NB * NC;

    conv_kernel<<<3072, 256, 0, stream>>>(W1, W2, Wc, wb);

    const int fs_lds = 2 * 64 * 256 * 2;  // 65536 B dynamic (+1KB static part[])
    hipFuncSetAttribute((const void*)fs_kernel,
                        hipFuncAttributeMaxDynamicSharedMemorySize, fs_lds);
    fs_kernel<<<2048, 256, fs_lds, stream>>>(x, proto, var, W1b, b1, W2b, b2,
                                             W3, b3, ridx, fsi);
    cons_kernel<<<512, 512, 0, stream>>>(x, Wcb, bc, fsi, ridx, outp, fire_out);
}

// Round 11
// 175.875 us; speedup vs baseline: 2.0171x; 1.0934x over previous
//
#include <hip/hip_runtime.h>
#include <hip/hip_bf16.h>
#include <cstdint>
#include <cstddef>

#define NF 256   // features
#define NG 512   // hidden (2F)
#define NC 64    // classes
#define NB 8192  // batch
#define NK 16    // active rules
#define BT 64    // fs batch tile

typedef __attribute__((ext_vector_type(8))) short short8;
typedef __attribute__((ext_vector_type(4))) float floatx4;

__device__ __forceinline__ unsigned short f2bf(float f) {
    union { float f; unsigned int u; } a; a.f = f;
    unsigned int u = a.u;
    u += 0x7fffu + ((u >> 16) & 1u);   // RNE
    return (unsigned short)(u >> 16);
}
__device__ __forceinline__ float elu1(float z) {
    return z > 0.0f ? z : (__expf(z) - 1.0f);
}
// HW-packed f32x2 -> bf16x2 (v_cvt_pk_bf16_f32, RNE — bit-identical to f2bf)
__device__ __forceinline__ unsigned int pk2bf(float a, float b) {
    __hip_bfloat162 h = __float22bfloat162_rn(make_float2(a, b));
    union { __hip_bfloat162 h; unsigned int u; } cv; cv.h = h; return cv.u;
}

// LDS-only barrier: orders ds ops across the workgroup WITHOUT draining vmcnt.
__device__ __forceinline__ void bar_lds() {
    __builtin_amdgcn_sched_barrier(0);
    asm volatile("s_waitcnt lgkmcnt(0)" ::: "memory");
    __builtin_amdgcn_s_barrier();
    __builtin_amdgcn_sched_barrier(0);
}

// ---------------- kernel 0: weights fp32 -> bf16, ALL FRAGMENT-TRANSPOSED ----
// W1t/W2t (as in round 10) and now Wct too: fragment (r, N-block, K-block) is
// a contiguous 1024 B run; element ((f*64 + lane)*8 + e) maps to
// Wc[r][N*16 + (lane&15)][K*32 + (lane>>4)*8 + e].  cons B-loads become
// base + k0i*512 immediate — one contiguous 1KB request per instruction
// instead of 16 scattered 64B requests (the same fix that took fs 155->95us).
// Same f2bf bits -> FP-identical results.
__global__ __launch_bounds__(256) void conv_kernel(
    const float* __restrict__ W1, const float* __restrict__ W2,
    const float* __restrict__ Wc, unsigned short* __restrict__ wb)
{
    int i = blockIdx.x * 256 + threadIdx.x;
    if (i < 131072) {            // W1t: 32 N-blocks x 8 K-blocks
        int e = i & 7, l = (i >> 3) & 63, K = (i >> 9) & 7, N = i >> 12;
        int src = (N * 16 + (l & 15)) * NF + K * 32 + (l >> 4) * 8 + e;
        wb[i] = f2bf(W1[src]);
    } else if (i < 262144) {     // W2t: 16 N-blocks x 16 K-blocks
        int o = i - 131072;
        int e = o & 7, l = (o >> 3) & 63, K = (o >> 9) & 15, N = o >> 13;
        int src = (N * 16 + (l & 15)) * NG + K * 32 + (l >> 4) * 8 + e;
        wb[i] = f2bf(W2[src]);
    } else if (i < 786432) {     // Wct: 32 rules x 4 N-blocks x 8 K-blocks
        int o = i - 262144;
        int e = o & 7, l = (o >> 3) & 63, K = (o >> 9) & 7, N = (o >> 12) & 3, r = o >> 14;
        int src = (r * NC + N * 16 + (l & 15)) * NF + K * 32 + (l >> 4) * 8 + e;
        wb[i] = f2bf(Wc[src]);
    }
}

// ---------------- kernel 1: fused membership -> MLP -> fsi -------------------
// UNCHANGED from round 10 (verified 95-97us): rolled loops, swizzled LDS,
// XCD swizzle, bar_lds, fragment-contiguous W1t/W2t loads, pk2bf, exp2 fold.
__global__ __launch_bounds__(256, 2) void fs_kernel(
    const float* __restrict__ x, const float* __restrict__ proto,
    const float* __restrict__ var, const unsigned short* __restrict__ W1b,
    const float* __restrict__ b1, const unsigned short* __restrict__ W2b,
    const float* __restrict__ b2, const float* __restrict__ W3,
    const float* __restrict__ b3, const int* __restrict__ ridx,
    float* __restrict__ fsi)
{
    extern __shared__ unsigned short smem[];
    __shared__ float part[4][64];
    unsigned short* mv   = smem;              // [64][256] swizzled (512 B rows)
    unsigned short* cbuf = smem + 64 * 256;   // [64][256] swizzled, reused per chunk

    const int t   = threadIdx.x;
    // XCD-chunked swizzle (bijective, 2048%8==0); keeps x/weights L2-resident
    const int pid = blockIdx.x;
    const int lg  = (pid & 7) * 256 + (pid >> 3);
    const int kidx = lg & 15;
    const int tile = lg >> 4;
    const int r    = ridx[kidx];
    const int b0   = tile * BT;

    const int wave = t >> 6, lane = t & 63;
    const int ln = lane & 15, lq = lane >> 4;
    const int sxr = (ln & 7) << 4;            // swizzle term (row&7 == ln&7)

    // ---- P0: membership mv = exp(-(x-p)^2/(2 v^2)), v=clip(var,1e-4,0.1) ----
    {
        const int col   = (t & 63) * 4;
        const int colb  = (t & 63) * 8;
        const int rbase = t >> 6;             // 0..3
        const float4 p4 = *(const float4*)(proto + (size_t)r * NF + col);
        float4 v4 = *(const float4*)(var + (size_t)r * NF + col);
        float cx = fminf(fmaxf(v4.x, 1e-4f), 0.1f);
        float cy = fminf(fmaxf(v4.y, 1e-4f), 0.1f);
        float cz = fminf(fmaxf(v4.z, 1e-4f), 0.1f);
        float cw = fminf(fmaxf(v4.w, 1e-4f), 0.1f);
        const float L2E = 1.44269504088896340736f;   // fold log2e: __expf(z)
        float ix = (0.5f * L2E) / (cx * cx);         // == exp2(z*log2e)
        float iy = (0.5f * L2E) / (cy * cy);
        float iz = (0.5f * L2E) / (cz * cz);
        float iw = (0.5f * L2E) / (cw * cw);
#pragma unroll 4
        for (int i = 0; i < 16; ++i) {
            int row = i * 4 + rbase;
            const float4 xv = *(const float4*)(x + (size_t)(b0 + row) * NF + col);
            float dx = xv.x - p4.x, dy = xv.y - p4.y, dz = xv.z - p4.z, dw = xv.w - p4.w;
            uint2 pk;
            pk.x = pk2bf(exp2f(-dx * dx * ix), exp2f(-dy * dy * iy));
            pk.y = pk2bf(exp2f(-dz * dz * iz), exp2f(-dw * dw * iw));
            *(uint2*)((char*)mv + row * 512 + (colb ^ ((row & 7) << 4))) = pk;
        }
    }
    bar_lds();

    // persistent h2 accumulator: n' = wave*64 + mi*16 + lq*4 + rg, b = ni*16 + ln
    floatx4 acc2[4][4];
#pragma unroll
    for (int mi = 0; mi < 4; ++mi)
#pragma unroll
        for (int ni = 0; ni < 4; ++ni) {
            floatx4 z = {0.0f, 0.0f, 0.0f, 0.0f};
            acc2[mi][ni] = z;
        }

#pragma unroll 1
    for (int c = 0; c < 2; ++c) {
        // ---- P1 chunk c: h1^T for n in [c*256, c*256+256) ----
        floatx4 acc1[4][4];
#pragma unroll
        for (int mi = 0; mi < 4; ++mi)
#pragma unroll
            for (int ni = 0; ni < 4; ++ni) {
                floatx4 z = {0.0f, 0.0f, 0.0f, 0.0f};
                acc1[mi][ni] = z;
            }
        const unsigned short* w1p = W1b + c * 65536 + wave * 16384 + lane * 8;
#pragma unroll 2
        for (int k0i = 0; k0i < 8; ++k0i) {
            short8 a[4], b[4];
#pragma unroll
            for (int mi = 0; mi < 4; ++mi)
                a[mi] = *(const short8*)(w1p + mi * 4096 + k0i * 512);
#pragma unroll
            for (int ni = 0; ni < 4; ++ni)
                b[ni] = *(const short8*)((const char*)mv + (ni * 16 + ln) * 512
                                         + ((k0i * 64 + lq * 16) ^ sxr));
#pragma unroll
            for (int ni = 0; ni < 4; ++ni)
#pragma unroll
                for (int mi = 0; mi < 4; ++mi)
                    acc1[mi][ni] = __builtin_amdgcn_mfma_f32_16x16x32_bf16(
                        a[mi], b[ni], acc1[mi][ni], 0, 0, 0);
        }
        bar_lds();   // prior chunk's P2 reads of cbuf are done
        // ---- ELU + bias -> cbuf (swizzled; 4 consecutive n per lane) ----
#pragma unroll
        for (int mi = 0; mi < 4; ++mi) {
            const int nl = wave * 64 + mi * 16 + lq * 4;   // chunk-local n
            const float4 b4 = *(const float4*)(b1 + c * 256 + nl);
#pragma unroll
            for (int ni = 0; ni < 4; ++ni) {
                uint2 pk;
                pk.x = pk2bf(elu1(acc1[mi][ni][0] + b4.x),
                             elu1(acc1[mi][ni][1] + b4.y));
                pk.y = pk2bf(elu1(acc1[mi][ni][2] + b4.z),
                             elu1(acc1[mi][ni][3] + b4.w));
                *(uint2*)((char*)cbuf + (ni * 16 + ln) * 512 + ((nl * 2) ^ sxr)) = pk;
            }
        }
        bar_lds();
        // ---- P2 chunk c: acc2 += W2[:, c*256:+256] @ h1_c^T ----
        const unsigned short* w2p = W2b + wave * 32768 + c * 8 * 512 + lane * 8;
#pragma unroll 2
        for (int k0i = 0; k0i < 8; ++k0i) {
            short8 a[4], b[4];
#pragma unroll
            for (int mi = 0; mi < 4; ++mi)
                a[mi] = *(const short8*)(w2p + mi * 8192 + k0i * 512);
#pragma unroll
            for (int ni = 0; ni < 4; ++ni)
                b[ni] = *(const short8*)((const char*)cbuf + (ni * 16 + ln) * 512
                                         + ((k0i * 64 + lq * 16) ^ sxr));
#pragma unroll
            for (int ni = 0; ni < 4; ++ni)
#pragma unroll
                for (int mi = 0; mi < 4; ++mi)
                    acc2[mi][ni] = __builtin_amdgcn_mfma_f32_16x16x32_bf16(
                        a[mi], b[ni], acc2[mi][ni], 0, 0, 0);
        }
    }

    // ---- P3: fsi[b] = b3 + sum_n' ELU(h2[b][n'] + b2) * W3[n'] ----
    float w3v[4][4], b2v[4][4];
#pragma unroll
    for (int mi = 0; mi < 4; ++mi) {
        const int np = wave * 64 + mi * 16 + lq * 4;
        const float4 wv = *(const float4*)(W3 + np);
        const float4 bv = *(const float4*)(b2 + np);
        w3v[mi][0] = wv.x; w3v[mi][1] = wv.y; w3v[mi][2] = wv.z; w3v[mi][3] = wv.w;
        b2v[mi][0] = bv.x; b2v[mi][1] = bv.y; b2v[mi][2] = bv.z; b2v[mi][3] = bv.w;
    }
#pragma unroll
    for (int ni = 0; ni < 4; ++ni) {
        float s = 0.0f;
#pragma unroll
        for (int mi = 0; mi < 4; ++mi)
#pragma unroll
            for (int rg = 0; rg < 4; ++rg)
                s += elu1(acc2[mi][ni][rg] + b2v[mi][rg]) * w3v[mi][rg];
        s += __shfl_xor(s, 16);
        s += __shfl_xor(s, 32);
        if (lq == 0) part[wave][ni * 16 + ln] = s;
    }
    bar_lds();
    if (t < 64) {
        float s = b3[0];
#pragma unroll
        for (int w = 0; w < 4; ++w) s += part[w][t];
        fsi[(size_t)kidx * NB + b0 + t] = s;
    }
}

// ---------------- kernel 2: softmax over rules + consequent + weighted sum ----
// grid: 512 blocks x 512 threads; block = 16 batch rows, 64 classes.
// Wct is fragment-transposed: per (rule, class-block) the B-operand is
// base + k0i*512 (contiguous 1KB/instruction) — no scattered requests, no
// per-step address VALU. Dual-rule unroll; same accumulation order as before
// -> bit-identical output.
__global__ __launch_bounds__(512, 4) void cons_kernel(
    const float* __restrict__ x, const unsigned short* __restrict__ Wcb,
    const float* __restrict__ bc, const float* __restrict__ fsi,
    const int* __restrict__ ridx, float* __restrict__ outp,
    float* __restrict__ fire_out)
{
    __shared__ unsigned short xl[16 * 264];
    __shared__ float fire[16][NK];
    __shared__ float pred[4][16][16];

    const int t  = threadIdx.x;
    const int b0 = blockIdx.x * 16;

    int rr[NK];
#pragma unroll
    for (int k = 0; k < NK; ++k) rr[k] = ridx[k];

    {
        int idx = t;
#pragma unroll
        for (int i = 0; i < 2; ++i, idx += 512) {
            int row = idx >> 6, col = (idx & 63) * 4;
            const float4 xv = *(const float4*)(x + (size_t)(b0 + row) * NF + col);
            uint2 pk;
            pk.x = pk2bf(xv.x, xv.y);
            pk.y = pk2bf(xv.z, xv.w);
            *(uint2*)(xl + row * 264 + col) = pk;
        }
    }
    if (t < 256) {
        const int row = t >> 4, k = t & 15;
        float v = fsi[(size_t)k * NB + b0 + row];
        float mx = v;
        mx = fmaxf(mx, __shfl_xor(mx, 1));
        mx = fmaxf(mx, __shfl_xor(mx, 2));
        mx = fmaxf(mx, __shfl_xor(mx, 4));
        mx = fmaxf(mx, __shfl_xor(mx, 8));
        float e = __expf(v - mx);
        float sum = e;
        sum += __shfl_xor(sum, 1);
        sum += __shfl_xor(sum, 2);
        sum += __shfl_xor(sum, 4);
        sum += __shfl_xor(sum, 8);
        float fv = e / sum;
        fire[row][k] = fv;
        fire_out[(size_t)b0 * NK + t] = fv;
    }
    __syncthreads();

    const int wave = t >> 6, lane = t & 63;
    const int ln = lane & 15, lq = lane >> 4;
    const int cg = wave & 3, half = wave >> 2;
    const int nb = cg * 16;

    short8 afr[8];
#pragma unroll
    for (int k0i = 0; k0i < 8; ++k0i)
        afr[k0i] = *(const short8*)(xl + ln * 264 + k0i * 32 + lq * 8);

    floatx4 oacc = {0.0f, 0.0f, 0.0f, 0.0f};
#pragma unroll
    for (int kp = 0; kp < 4; ++kp) {
        const int k0r = half * 8 + kp * 2;
        const int r0 = rr[k0r], r1 = rr[k0r + 1];
        // fragment-major: frag (r, cg, k0i) at ((r*4 + cg)*8 + k0i)*512 ushorts
        const unsigned short* Wr0 = Wcb + ((size_t)(r0 * 4 + cg) * 8) * 512 + lane * 8;
        const unsigned short* Wr1 = Wcb + ((size_t)(r1 * 4 + cg) * 8) * 512 + lane * 8;
        floatx4 a0 = {0.0f, 0.0f, 0.0f, 0.0f};
        floatx4 a1 = {0.0f, 0.0f, 0.0f, 0.0f};
#pragma unroll
        for (int k0i = 0; k0i < 8; ++k0i) {
            short8 bb0 = *(const short8*)(Wr0 + k0i * 512);
            short8 bb1 = *(const short8*)(Wr1 + k0i * 512);
            a0 = __builtin_amdgcn_mfma_f32_16x16x32_bf16(afr[k0i], bb0, a0, 0, 0, 0);
            a1 = __builtin_amdgcn_mfma_f32_16x16x32_bf16(afr[k0i], bb1, a1, 0, 0, 0);
        }
        const float bias0 = bc[(size_t)r0 * NC + nb + ln];
        const float bias1 = bc[(size_t)r1 * NC + nb + ln];
#pragma unroll
        for (int rg = 0; rg < 4; ++rg) {
            const int row = lq * 4 + rg;
            oacc[rg] += fmaxf(a0[rg] + bias0, 0.0f) * fire[row][k0r]
                      + fmaxf(a1[rg] + bias1, 0.0f) * fire[row][k0r + 1];
        }
    }
    if (half == 1) {
#pragma unroll
        for (int rg = 0; rg < 4; ++rg)
            pred[cg][lq * 4 + rg][ln] = oacc[rg];
    }
    __syncthreads();
    if (half == 0) {
#pragma unroll
        for (int rg = 0; rg < 4; ++rg)
            outp[(size_t)(b0 + lq * 4 + rg) * NC + nb + ln] =
                oacc[rg] + pred[cg][lq * 4 + rg][ln];
    }
}

extern "C" void kernel_launch(void* const* d_in, const int* in_sizes, int n_in,
                              void* d_out, int out_size, void* d_ws, size_t ws_size,
                              hipStream_t stream)
{
    (void)in_sizes; (void)n_in; (void)out_size;
    if (ws_size < 2097152) return;

    const float* x     = (const float*)d_in[0];
    const float* proto = (const float*)d_in[1];
    const float* var   = (const float*)d_in[2];
    const float* W1    = (const float*)d_in[3];
    const float* b1    = (const float*)d_in[4];
    const float* W2    = (const float*)d_in[5];
    const float* b2    = (const float*)d_in[6];
    const float* W3    = (const float*)d_in[7];
    const float* b3    = (const float*)d_in[8];
    const float* Wc    = (const float*)d_in[9];
    const float* bc    = (const float*)d_in[10];
    const int*   ridx  = (const int*)d_in[11];

    unsigned short* wb  = (unsigned short*)d_ws;
    unsigned short* W1b = wb;                 // 131072 (fragment-transposed)
    unsigned short* W2b = wb + 131072;        // 131072 (fragment-transposed)
    unsigned short* Wcb = wb + 262144;        // 524288 (fragment-transposed)
    float* fsi = (float*)((char*)d_ws + (size_t)786432 * 2);

    float* outp     = (float*)d_out;
    float* fire_out = outp + (size_t)NB * NC;

    conv_kernel<<<3072, 256, 0, stream>>>(W1, W2, Wc, wb);

    const int fs_lds = 2 * 64 * 256 * 2;  // 65536 B dynamic (+1KB static part[])
    hipFuncSetAttribute((const void*)fs_kernel,
                        hipFuncAttributeMaxDynamicSharedMemorySize, fs_lds);
    fs_kernel<<<2048, 256, fs_lds, stream>>>(x, proto, var, W1b, b1, W2b, b2,
                                             W3, b3, ridx, fsi);
    cons_kernel<<<512, 512, 0, stream>>>(x, Wcb, bc, fsi, ridx, outp, fire_out);
}